// Round 1
// baseline (223.685 us; speedup 1.0000x reference)
//
#include <hip/hip_runtime.h>
#include <math.h>

// NuclearLoss: cls_score (8,19,512,512) fp32 -> scalar fp32.
// loss = -(1/B) * sum over patches,channels of sqrt( sum_pixels softmax(x)[c]^2 )
// B = 8 * 32 * 32 = 8192 patches of 16x16.

#define NIMG 8
#define CCH  19
#define HH   512
#define WW   512
#define CHST (HH * WW)          // channel stride in floats (262144)

// Block: 256 threads cover a 16-row x 64-col region = 4 full 16x16 patches.
// Wave w (tids 64w..64w+63) handles rows (16*prow + w + {0,4,8,12}), cols w0..w0+63.
// Lane -> col, so each channel read is one coalesced 256B global_load_dword.
__global__ __launch_bounds__(256, 4) void nuclear_loss_kernel(
    const float* __restrict__ in, float* __restrict__ out) {
    __shared__ float psum[4 * CCH];  // per-(local patch, channel) diag sums

    const int tid = threadIdx.x;
    const int b   = blockIdx.x;
    const int n    = b >> 8;       // 256 blocks per image
    const int rem  = b & 255;
    const int prow = rem >> 3;     // patch row 0..31
    const int creg = rem & 7;      // 64-col region 0..7
    const int col  = (creg << 6) + (tid & 63);
    const int row0 = (prow << 4) + (tid >> 6);
    const int plocal = (tid & 63) >> 4;  // which of the 4 patches this lane is in

    for (int i = tid; i < 4 * CCH; i += 256) psum[i] = 0.0f;
    __syncthreads();

    float part[CCH];
#pragma unroll
    for (int c = 0; c < CCH; ++c) part[c] = 0.0f;

    const float* base = in + (size_t)n * CCH * CHST + (size_t)row0 * WW + col;

#pragma unroll
    for (int i = 0; i < 4; ++i) {
        const float* p = base + (size_t)(i * 4) * WW;  // rows row0, +4, +8, +12
        float e[CCH];
        float s = 0.0f;
#pragma unroll
        for (int c = 0; c < CCH; ++c) {
            // no max-subtraction: inputs ~N(0,1), exp stays well inside fp32
            e[c] = __expf(p[(size_t)c * CHST]);
            s += e[c];
        }
        const float inv = 1.0f / s;
#pragma unroll
        for (int c = 0; c < CCH; ++c) {
            const float t = e[c] * inv;      // softmax prob
            part[c] = fmaf(t, t, part[c]);   // accumulate prob^2
        }
    }

    // Reduce across the 16 lanes of each patch segment (patch width == 16).
#pragma unroll
    for (int c = 0; c < CCH; ++c) {
        float v = part[c];
        v += __shfl_down(v, 8, 16);
        v += __shfl_down(v, 4, 16);
        v += __shfl_down(v, 2, 16);
        v += __shfl_down(v, 1, 16);
        part[c] = v;
    }

    // Segment leaders (4 per wave, 4 waves) accumulate into LDS per-patch sums.
    if ((tid & 15) == 0) {
#pragma unroll
        for (int c = 0; c < CCH; ++c)
            atomicAdd(&psum[plocal * CCH + c], part[c]);
    }
    __syncthreads();

    // Wave 0: sqrt the 76 diag entries, sum, single global atomic per block.
    if (tid < 64) {
        float v = (tid < 4 * CCH) ? sqrtf(psum[tid]) : 0.0f;
        if (tid + 64 < 4 * CCH) v += sqrtf(psum[tid + 64]);
        v += __shfl_down(v, 32, 64);
        v += __shfl_down(v, 16, 64);
        v += __shfl_down(v, 8, 64);
        v += __shfl_down(v, 4, 64);
        v += __shfl_down(v, 2, 64);
        v += __shfl_down(v, 1, 64);
        if (tid == 0) atomicAdd(out, v * (-1.0f / 8192.0f));
    }
}

extern "C" void kernel_launch(void* const* d_in, const int* in_sizes, int n_in,
                              void* d_out, int out_size, void* d_ws, size_t ws_size,
                              hipStream_t stream) {
    const float* in = (const float*)d_in[0];
    float* out = (float*)d_out;
    // d_out is poisoned to 0xAA before every call; zero it (capturable memset node).
    hipMemsetAsync(out, 0, sizeof(float), stream);
    // 8 images * 32 patch-rows * 8 col-regions = 2048 blocks
    nuclear_loss_kernel<<<2048, 256, 0, stream>>>(in, out);
}